// Round 12
// baseline (550.912 us; speedup 1.0000x reference)
//
#include <hip/hip_runtime.h>
#include <math.h>

constexpr int NN = 10000;
constexpr int EE = 320000;
constexpr int H  = 4;
constexpr int D  = 64;
constexpr int C  = 16;
constexpr int IN = 256;
constexpr int HD = H * D; // 256

typedef __attribute__((ext_vector_type(8))) short bf16x8;
typedef __attribute__((ext_vector_type(4))) float f32x4;

__device__ __forceinline__ unsigned short f2b(float x) {
    unsigned int b = __float_as_uint(x);
    return (unsigned short)((b + 0x7FFFu + ((b >> 16) & 1u)) >> 16); // RNE bf16
}
__device__ __forceinline__ float b2f(unsigned short u) {
    return __uint_as_float((unsigned int)u << 16);
}

// ---- workspace layout (float-element offsets) ----
constexpr long OFF_FB   = 0;                               // N*HD bf16 = N*HD/2 floats
constexpr long OFF_EL   = OFF_FB   + (long)NN * HD / 2;    // N*H
constexpr long OFF_ER   = OFF_EL   + (long)NN * H;         // N*H
constexpr long OFF_F1   = OFF_ER   + (long)NN * H;         // N*H
constexpr long OFF_F2   = OFF_F1   + (long)NN * H;         // N*H
constexpr long OFF_AGG  = OFF_F2   + (long)NN * H;         // N*HD f32
constexpr long OFF_PRED = OFF_AGG  + (long)NN * HD;        // N   (int)
constexpr long OFF_SSRC = OFF_PRED + (long)NN;             // E   (int) src sorted by dst
constexpr long OFF_ROWP = OFF_SSRC + (long)EE;             // N+1 (int)
constexpr long OFF_RANK = OFF_ROWP + (long)NN + 1;         // E   (int) per-edge rank in dst
constexpr long OFF_DEGI = OFF_RANK + (long)EE;             // N   (int, zeroed by k_pack)
constexpr long OFF_CTR  = OFF_DEGI + (long)NN;             // 2 ints (zeroed by k_pack)
constexpr long OFF_SUM  = OFF_CTR  + 2;                    // 4 f32 (written by k_agg tail)
constexpr long OFF_WP   = OFF_SUM  + 4;                    // 65536 bf16 = 32768 floats
constexpr long OFF_HA   = OFF_WP   + 32768;                // N*IN bf16 A-frag table
constexpr long WS_END   = OFF_HA + (long)NN * IN / 2;

constexpr int GEMB = NN / 16;          // 625 MFMA-gemm blocks
constexpr int PB   = (NN + 255) / 256; // 40 pred blocks
constexpr int CB   = (EE + 255) / 256; // 1250 count blocks
constexpr int ZB   = (NN + 255) / 256; // 40 zero blocks (in k_pack)
constexpr int HAB  = (NN / 16) * 8 * 64 / 256; // 1250 ha-transform blocks
constexpr int GRID_MAIN = GEMB + PB + CB; // 1915
constexpr int GRID_AGG  = NN / 4;         // 2500

// k_pack roles: [0,32) W->B-frag pack; [32,32+ZB) zero deg_i+counters;
// [32+ZB,...) h -> bf16 A-frag table ha.
__global__ __launch_bounds__(256) void k_pack(const float* __restrict__ W,
                                              const float* __restrict__ hin,
                                              unsigned short* __restrict__ wp,
                                              unsigned short* __restrict__ ha,
                                              int* __restrict__ deg_i,
                                              int* __restrict__ ctr) {
    int bid = blockIdx.x;
    int t = threadIdx.x;
    if (bid < 32) {
        int tg = bid * 256 + t; // [0, 8192)
        int l  = tg & 63;
        int ct = (tg >> 6) & 3;
        int ks = (tg >> 8) & 7;
        int w  = tg >> 11;
        int col = w * 64 + ct * 16 + (l & 15);
        int kb  = ks * 32 + (l >> 4) * 8;
        unsigned short v[8];
#pragma unroll
        for (int i = 0; i < 8; ++i) v[i] = f2b(W[(long)(kb + i) * HD + col]);
        ushort4* p = (ushort4*)(wp + (long)tg * 8);
        p[0] = make_ushort4(v[0], v[1], v[2], v[3]);
        p[1] = make_ushort4(v[4], v[5], v[6], v[7]);
    } else if (bid < 32 + ZB) {
        int n = (bid - 32) * 256 + t;
        if (n < NN) deg_i[n] = 0;
        if (n == 0) { ctr[0] = 0; ctr[1] = 0; }
    } else {
        int e = (bid - 32 - ZB) * 256 + t; // [0, 320000) exact
        int l = e & 63, ks = (e >> 6) & 7, tile = e >> 9;
        int row = tile * 16 + (l & 15);
        int k0  = ks * 32 + (l >> 4) * 8;
        const float* ap = hin + (long)row * IN + k0;
        float4 a0 = *(const float4*)(ap);
        float4 a1 = *(const float4*)(ap + 4);
        ushort4* p = (ushort4*)(ha + (long)e * 8);
        p[0] = make_ushort4(f2b(a0.x), f2b(a0.y), f2b(a0.z), f2b(a0.w));
        p[1] = make_ushort4(f2b(a1.x), f2b(a1.y), f2b(a1.z), f2b(a1.w));
    }
}

// fused main kernel: MFMA gemm / pred / count+rank, then last-done block
// performs the exclusive scan (fold of the old k_scan dispatch).
__global__ __launch_bounds__(256) void k_main(const unsigned short* __restrict__ ha,
                                              const unsigned short* __restrict__ wp,
                                              const float* __restrict__ al,
                                              const float* __restrict__ ar,
                                              const float* __restrict__ logits,
                                              const int*   __restrict__ dst,
                                              unsigned short* __restrict__ featb,
                                              float* __restrict__ el,
                                              float* __restrict__ er,
                                              int*   __restrict__ pred,
                                              int*   __restrict__ deg_i,
                                              int*   __restrict__ rank,
                                              int*   __restrict__ rowptr,
                                              int*   __restrict__ ctr) {
    __shared__ int lastflag;
    __shared__ int wsum[4];
    int bid = blockIdx.x;
    int t = threadIdx.x;
    if (bid < GEMB) {
        int tile = bid;
        int w = t >> 6, l = t & 63;
        int g = l >> 4, fr = l & 15;

        f32x4 acc[4];
#pragma unroll
        for (int ct = 0; ct < 4; ++ct) acc[ct] = (f32x4){0.f, 0.f, 0.f, 0.f};

        const unsigned short* wpw = wp + (long)w * 8 * 4 * 64 * 8;
        const unsigned short* hap = ha + (long)tile * 8 * 64 * 8;

        for (int ks = 0; ks < 8; ++ks) {
            bf16x8 af = *(const bf16x8*)(hap + ((long)ks * 64 + l) * 8);
#pragma unroll
            for (int ct = 0; ct < 4; ++ct) {
                bf16x8 bfr = *(const bf16x8*)(wpw + (((long)ks * 4 + ct) * 64 + l) * 8);
                acc[ct] = __builtin_amdgcn_mfma_f32_16x16x32_bf16(af, bfr, acc[ct], 0, 0, 0);
            }
        }

        float aLr[4], aRr[4];
#pragma unroll
        for (int ct = 0; ct < 4; ++ct) {
            aLr[ct] = al[w * 64 + ct * 16 + fr];
            aRr[ct] = ar[w * 64 + ct * 16 + fr];
        }
#pragma unroll
        for (int j = 0; j < 4; ++j) {
            int row = tile * 16 + g * 4 + j;
            float vl = 0.f, vr = 0.f;
#pragma unroll
            for (int ct = 0; ct < 4; ++ct) {
                float v = acc[ct][j];
                featb[(long)row * HD + w * 64 + ct * 16 + fr] = f2b(v);
                vl = fmaf(v, aLr[ct], vl);
                vr = fmaf(v, aRr[ct], vr);
            }
            vl += __shfl_xor(vl, 1); vl += __shfl_xor(vl, 2);
            vl += __shfl_xor(vl, 4); vl += __shfl_xor(vl, 8);
            vr += __shfl_xor(vr, 1); vr += __shfl_xor(vr, 2);
            vr += __shfl_xor(vr, 4); vr += __shfl_xor(vr, 8);
            if (fr == 0) {
                el[(long)row * H + w] = vl;
                er[(long)row * H + w] = vr;
            }
        }
    } else if (bid < GEMB + PB) {
        int n = (bid - GEMB) * 256 + t;
        if (n < NN) {
            const float* row = logits + (long)n * C;
            float best = row[0]; int bi = 0;
#pragma unroll
            for (int c = 1; c < C; ++c) { float v = row[c]; if (v > best) { best = v; bi = c; } }
            pred[n] = bi;
        }
    } else {
        int e = (bid - GEMB - PB) * 256 + t;
        if (e < EE) rank[e] = atomicAdd(&deg_i[dst[e]], 1);
    }

    // ---- last-done block performs the scan (saves a dispatch) ----
    __threadfence();
    if (t == 0) lastflag = (atomicAdd(&ctr[0], 1) == GRID_MAIN - 1);
    __syncthreads();
    if (!lastflag) return;
    __threadfence();
    int lane = t & 63, wid = t >> 6;
    constexpr int CH = (NN + 255) / 256; // 40
    int base = t * CH;
    int s = 0;
    for (int i = 0; i < CH; ++i) { int idx = base + i; if (idx < NN) s += deg_i[idx]; }
    int incl = s;
    for (int off = 1; off < 64; off <<= 1) {
        int v = __shfl_up(incl, off);
        if (lane >= off) incl += v;
    }
    if (lane == 63) wsum[wid] = incl;
    __syncthreads();
    if (t < 4) {
        int v = wsum[t], inc2 = v;
        for (int off = 1; off < 4; off <<= 1) {
            int u = __shfl_up(inc2, off);
            if (t >= off) inc2 += u;
        }
        wsum[t] = inc2 - v;
    }
    __syncthreads();
    int run = wsum[wid] + incl - s;
    for (int i = 0; i < CH; ++i) {
        int idx = base + i;
        if (idx < NN) { int dd = deg_i[idx]; rowptr[idx] = run; run += dd; }
    }
    if (t == 255) rowptr[NN] = run; // == EE
}

// atomic-free scatter: slot = rowptr[dst] + rank (unique by construction)
__global__ __launch_bounds__(256) void k_scatter(const int* __restrict__ src,
                                                 const int* __restrict__ dst,
                                                 const int* __restrict__ rank,
                                                 const int* __restrict__ rowptr,
                                                 int* __restrict__ ssrc) {
    int e = blockIdx.x * 256 + threadIdx.x;
    if (e >= EE) return;
    ssrc[rowptr[dst[e]] + rank[e]] = src[e];
}

// one wave per dst node; last-done block folds the f1/f2 global reduction
// (replaces the k_sum dispatch).
#define EDGE(kk) { \
    int spk = __builtin_amdgcn_readlane(sp, (kk)); \
    int s_  = spk & 0xFFFF; \
    int ps_ = spk >> 16; \
    float wa = __shfl(w, (hidx << 4) | (kk)); \
    const ushort4 f = *(const ushort4*)(featb + (long)s_ * HD + (lane << 2)); \
    acc.x = fmaf(wa, b2f(f.x), acc.x); \
    acc.y = fmaf(wa, b2f(f.y), acc.y); \
    acc.z = fmaf(wa, b2f(f.z), acc.z); \
    acc.w = fmaf(wa, b2f(f.w), acc.w); \
    f1a += (ps_ == pd)   ? wa : 0.f; \
    ca  += (ps_ == cidx) ? wa : 0.f; \
}

__global__ __launch_bounds__(256) void k_agg(const int* __restrict__ rowptr,
                                             const int* __restrict__ ssrc,
                                             const float* __restrict__ el,
                                             const float* __restrict__ er,
                                             const unsigned short* __restrict__ featb,
                                             const int* __restrict__ pred,
                                             float* __restrict__ agg,
                                             float* __restrict__ f1,
                                             float* __restrict__ f2,
                                             int* __restrict__ ctr,
                                             float* __restrict__ sums) {
    __shared__ int lastflag;
    __shared__ float red[4][4];
    int lane = threadIdx.x & 63;
    int n = blockIdx.x * 4 + (threadIdx.x >> 6); // grid = NN/4 exactly
    int beg = rowptr[n], end = rowptr[n + 1];
    int deg = end - beg;
    int hidx = lane >> 4, cidx = lane & 15;
    float Rh = er[(long)n * H + hidx];
    int pd = pred[n];

    float4 acc = {0.f, 0.f, 0.f, 0.f};
    float dsum = 0.f, f1a = 0.f, ca = 0.f;

    for (int base = beg; base < end; base += 16) {
        int nk = end - base; if (nk > 16) nk = 16;
        float w = 0.f; int sp = 0;
        if (cidx < nk) {
            int s = ssrc[base + cidx];
            float x = el[(long)s * H + hidx] + Rh;
            x = x > 0.f ? x : 0.2f * x;
            w = __expf(x);
            if (hidx == 0) sp = s | (pred[s] << 16);
        }
        dsum += w;
        if (nk == 16) {
#pragma unroll
            for (int k = 0; k < 16; ++k) EDGE(k)
        } else {
            for (int k = 0; k < nk; ++k) EDGE(k)
        }
    }

    for (int off = 1; off < 16; off <<= 1) dsum += __shfl_xor(dsum, off);
    float invh = dsum > 0.f ? 1.f / dsum : 0.f;
    float invdeg = 1.0f / (float)(deg > 0 ? deg : 1);

    float4 o;
    o.x = acc.x * invh; o.y = acc.y * invh; o.z = acc.z * invh; o.w = acc.w * invh;
    *(float4*)(agg + (long)n * HD + (lane << 2)) = o;

    float v = fmaxf(ca * invh * invdeg, 1e-5f);
    float term = -v * logf(v);
    for (int off = 1; off < 16; off <<= 1) term += __shfl_xor(term, off);
    if (cidx == 0) {
        f1[(long)n * H + hidx] = f1a * invh * invdeg;
        f2[(long)n * H + hidx] = term;
    }

    // ---- last-done block reduces f1/f2 -> sums[4] ----
    __threadfence();
    if (threadIdx.x == 0) lastflag = (atomicAdd(&ctr[1], 1) == GRID_AGG - 1);
    __syncthreads();
    if (!lastflag) return;
    __threadfence();
    float s1 = 0.f, q1 = 0.f, s2 = 0.f, q2 = 0.f;
    for (int i = threadIdx.x; i < NN * H; i += 256) {
        float a = f1[i], b = f2[i];
        s1 += a; q1 = fmaf(a, a, q1);
        s2 += b; q2 = fmaf(b, b, q2);
    }
    for (int off = 32; off; off >>= 1) {
        s1 += __shfl_down(s1, off);
        q1 += __shfl_down(q1, off);
        s2 += __shfl_down(s2, off);
        q2 += __shfl_down(q2, off);
    }
    int wid = threadIdx.x >> 6;
    if ((threadIdx.x & 63) == 0) {
        red[wid][0] = s1; red[wid][1] = q1; red[wid][2] = s2; red[wid][3] = q2;
    }
    __syncthreads();
    if (threadIdx.x < 4) {
        float a = 0.f;
        for (int wv = 0; wv < 4; ++wv) a += red[wv][threadIdx.x];
        sums[threadIdx.x] = a;
    }
}

// fused: z/gate (LayerNorm'd f1,f2) + final output. 4 elems/thread,
// feat read in bf16 (f32 feat buffer eliminated).
__global__ __launch_bounds__(256) void k_out(const unsigned short* __restrict__ featb,
                                             const float* __restrict__ agg,
                                             const float* __restrict__ f1,
                                             const float* __restrict__ f2,
                                             const float* __restrict__ sums,
                                             const float* __restrict__ old_z,
                                             const float* __restrict__ tau1,
                                             const float* __restrict__ tau2,
                                             const int* __restrict__ rowptr,
                                             float* __restrict__ out,
                                             float* __restrict__ zout) {
    long i4 = ((long)blockIdx.x * 256 + threadIdx.x) * 4;
    if (i4 >= (long)NN * HD) return;
    int n = (int)(i4 >> 8);
    int h = (int)((i4 >> 6) & 3);
    int t = n * H + h;
    constexpr float invNH = 1.0f / (NN * H);
    float mu1 = sums[0] * invNH, mu2 = sums[2] * invNH;
    float v1 = fmaxf(sums[1] * invNH - mu1 * mu1, 0.f);
    float v2 = fmaxf(sums[3] * invNH - mu2 * mu2, 0.f);
    float r1 = rsqrtf(v1 + 1e-5f), r2 = rsqrtf(v2 + 1e-5f);
    float nf1 = (f1[t] - mu1) * r1;
    float nf2 = (f2[t] - mu2) * r2;
    float z = (1.f / (1.f + expf(nf1 - tau1[0]))) * (1.f / (1.f + expf(nf2 - tau2[0])));
    float gate = fminf(old_z[t], z);
    if ((i4 & 63) == 0) zout[t] = z;
    int deg = rowptr[n + 1] - rowptr[n];
    float g = gate * rsqrtf((float)(deg > 0 ? deg : 1));
    const ushort4 fb = *(const ushort4*)(featb + i4);
    const float4 ag = *(const float4*)(agg + i4);
    float4 o;
    o.x = fmaf(g, ag.x, b2f(fb.x));
    o.y = fmaf(g, ag.y, b2f(fb.y));
    o.z = fmaf(g, ag.z, b2f(fb.z));
    o.w = fmaf(g, ag.w, b2f(fb.w));
    *(float4*)(out + i4) = o;
}

extern "C" void kernel_launch(void* const* d_in, const int* in_sizes, int n_in,
                              void* d_out, int out_size, void* d_ws, size_t ws_size,
                              hipStream_t stream) {
    const float* hin    = (const float*)d_in[0];
    const float* logits = (const float*)d_in[1];
    const float* old_z  = (const float*)d_in[2];
    const float* attn_l = (const float*)d_in[3];
    const float* attn_r = (const float*)d_in[4];
    const float* Wfc    = (const float*)d_in[5];
    const float* tau1   = (const float*)d_in[6];
    const float* tau2   = (const float*)d_in[7];
    const int*   src    = (const int*)d_in[8];
    const int*   dst    = (const int*)d_in[9];
    float* out = (float*)d_out;
    float* ws  = (float*)d_ws;

    unsigned short* featb = (unsigned short*)(ws + OFF_FB);
    unsigned short* wp    = (unsigned short*)(ws + OFF_WP);
    unsigned short* ha    = (unsigned short*)(ws + OFF_HA);
    int* pred   = (int*)(ws + OFF_PRED);
    int* ssrc   = (int*)(ws + OFF_SSRC);
    int* rowptr = (int*)(ws + OFF_ROWP);
    int* rank   = (int*)(ws + OFF_RANK);
    int* deg_i  = (int*)(ws + OFF_DEGI);
    int* ctr    = (int*)(ws + OFF_CTR);
    float* sums = ws + OFF_SUM;

    k_pack   <<<32 + ZB + HAB, 256, 0, stream>>>(Wfc, hin, wp, ha, deg_i, ctr);
    k_main   <<<GRID_MAIN, 256, 0, stream>>>(ha, wp, attn_l, attn_r, logits, dst,
                                             featb, ws + OFF_EL, ws + OFF_ER,
                                             pred, deg_i, rank, rowptr, ctr);
    k_scatter<<<(EE + 255) / 256, 256, 0, stream>>>(src, dst, rank, rowptr, ssrc);
    k_agg    <<<GRID_AGG, 256, 0, stream>>>(rowptr, ssrc, ws + OFF_EL, ws + OFF_ER,
                                            featb, pred,
                                            ws + OFF_AGG, ws + OFF_F1, ws + OFF_F2,
                                            ctr, sums);
    k_out    <<<(NN * HD / 4 + 255) / 256, 256, 0, stream>>>(featb, ws + OFF_AGG,
                                                             ws + OFF_F1, ws + OFF_F2, sums,
                                                             old_z, tau1, tau2, rowptr,
                                                             out, out + (long)NN * HD);
}

// Round 14
// 89.566 us; speedup vs baseline: 6.1509x; 6.1509x over previous
//
#include <hip/hip_runtime.h>
#include <math.h>

constexpr int NN = 10000;
constexpr int EE = 320000;
constexpr int H  = 4;
constexpr int D  = 64;
constexpr int C  = 16;
constexpr int IN = 256;
constexpr int HD = H * D; // 256

typedef __attribute__((ext_vector_type(8))) short bf16x8;
typedef __attribute__((ext_vector_type(4))) float f32x4;

__device__ __forceinline__ unsigned short f2b(float x) {
    unsigned int b = __float_as_uint(x);
    return (unsigned short)((b + 0x7FFFu + ((b >> 16) & 1u)) >> 16); // RNE bf16
}
__device__ __forceinline__ float b2f(unsigned short u) {
    return __uint_as_float((unsigned int)u << 16);
}

// ---- workspace layout (float-element offsets) ----
constexpr long OFF_FB   = 0;                               // N*HD bf16 = N*HD/2 floats
constexpr long OFF_EL   = OFF_FB   + (long)NN * HD / 2;    // N*H
constexpr long OFF_ER   = OFF_EL   + (long)NN * H;         // N*H
constexpr long OFF_F1   = OFF_ER   + (long)NN * H;         // N*H
constexpr long OFF_F2   = OFF_F1   + (long)NN * H;         // N*H
constexpr long OFF_AGG  = OFF_F2   + (long)NN * H;         // N*HD f32
constexpr long OFF_PRED = OFF_AGG  + (long)NN * HD;        // N   (int)
constexpr long OFF_SSRC = OFF_PRED + (long)NN;             // E   (int) src sorted by dst
constexpr long OFF_ROWP = OFF_SSRC + (long)EE;             // N+1 (int)
constexpr long OFF_RANK = OFF_ROWP + (long)NN + 1;         // E   (int) per-edge rank in dst
constexpr long OFF_DEGI = OFF_RANK + (long)EE;             // N   (int, zeroed by k_pack)
constexpr long OFF_SUM  = OFF_DEGI + (long)NN;             // 4 f32 (plain-stored by k_sum)
constexpr long OFF_WP   = OFF_SUM  + 4;                    // 65536 bf16 = 32768 floats
constexpr long OFF_HA   = OFF_WP   + 32768;                // N*IN bf16 A-frag table
constexpr long WS_END   = OFF_HA + (long)NN * IN / 2;

constexpr int GEMB = NN / 16;          // 625 MFMA-gemm blocks
constexpr int PB   = (NN + 255) / 256; // 40 pred blocks
constexpr int CB   = (EE + 255) / 256; // 1250 count blocks
constexpr int ZB   = (NN + 255) / 256; // 40 zero blocks (in k_pack)
constexpr int HAB  = (NN / 16) * 8 * 64 / 256; // 1250 ha-transform blocks

// k_pack roles: [0,32) W->B-frag pack; [32,32+ZB) zero deg_i;
// [32+ZB,...) h -> bf16 A-frag table ha.
__global__ __launch_bounds__(256) void k_pack(const float* __restrict__ W,
                                              const float* __restrict__ hin,
                                              unsigned short* __restrict__ wp,
                                              unsigned short* __restrict__ ha,
                                              int* __restrict__ deg_i) {
    int bid = blockIdx.x;
    int t = threadIdx.x;
    if (bid < 32) {
        int tg = bid * 256 + t; // [0, 8192)
        int l  = tg & 63;
        int ct = (tg >> 6) & 3;
        int ks = (tg >> 8) & 7;
        int w  = tg >> 11;
        int col = w * 64 + ct * 16 + (l & 15);
        int kb  = ks * 32 + (l >> 4) * 8;
        unsigned short v[8];
#pragma unroll
        for (int i = 0; i < 8; ++i) v[i] = f2b(W[(long)(kb + i) * HD + col]);
        ushort4* p = (ushort4*)(wp + (long)tg * 8);
        p[0] = make_ushort4(v[0], v[1], v[2], v[3]);
        p[1] = make_ushort4(v[4], v[5], v[6], v[7]);
    } else if (bid < 32 + ZB) {
        int n = (bid - 32) * 256 + t;
        if (n < NN) deg_i[n] = 0;
    } else {
        int e = (bid - 32 - ZB) * 256 + t; // [0, 320000) exact
        int l = e & 63, ks = (e >> 6) & 7, tile = e >> 9;
        int row = tile * 16 + (l & 15);
        int k0  = ks * 32 + (l >> 4) * 8;
        const float* ap = hin + (long)row * IN + k0;
        float4 a0 = *(const float4*)(ap);
        float4 a1 = *(const float4*)(ap + 4);
        ushort4* p = (ushort4*)(ha + (long)e * 8);
        p[0] = make_ushort4(f2b(a0.x), f2b(a0.y), f2b(a0.z), f2b(a0.w));
        p[1] = make_ushort4(f2b(a1.x), f2b(a1.y), f2b(a1.z), f2b(a1.w));
    }
}

// fused main kernel: blocks [0,GEMB) MFMA gemm, [GEMB,GEMB+PB) pred, rest
// count+rank (atomic return value = slot rank -> atomic-free scatter).
// (No end-of-kernel fence/fold: a per-block __threadfence here cost 5x by
// continuously invalidating L2 — round 12 post-mortem.)
__global__ __launch_bounds__(256) void k_main(const unsigned short* __restrict__ ha,
                                              const unsigned short* __restrict__ wp,
                                              const float* __restrict__ al,
                                              const float* __restrict__ ar,
                                              const float* __restrict__ logits,
                                              const int*   __restrict__ dst,
                                              unsigned short* __restrict__ featb,
                                              float* __restrict__ el,
                                              float* __restrict__ er,
                                              int*   __restrict__ pred,
                                              int*   __restrict__ deg_i,
                                              int*   __restrict__ rank) {
    int bid = blockIdx.x;
    int t = threadIdx.x;
    if (bid < GEMB) {
        int tile = bid;
        int w = t >> 6, l = t & 63;
        int g = l >> 4, fr = l & 15;

        f32x4 acc[4];
#pragma unroll
        for (int ct = 0; ct < 4; ++ct) acc[ct] = (f32x4){0.f, 0.f, 0.f, 0.f};

        const unsigned short* wpw = wp + (long)w * 8 * 4 * 64 * 8;
        const unsigned short* hap = ha + (long)tile * 8 * 64 * 8;

        for (int ks = 0; ks < 8; ++ks) {
            bf16x8 af = *(const bf16x8*)(hap + ((long)ks * 64 + l) * 8);
#pragma unroll
            for (int ct = 0; ct < 4; ++ct) {
                bf16x8 bfr = *(const bf16x8*)(wpw + (((long)ks * 4 + ct) * 64 + l) * 8);
                acc[ct] = __builtin_amdgcn_mfma_f32_16x16x32_bf16(af, bfr, acc[ct], 0, 0, 0);
            }
        }

        float aLr[4], aRr[4];
#pragma unroll
        for (int ct = 0; ct < 4; ++ct) {
            aLr[ct] = al[w * 64 + ct * 16 + fr];
            aRr[ct] = ar[w * 64 + ct * 16 + fr];
        }
#pragma unroll
        for (int j = 0; j < 4; ++j) {
            int row = tile * 16 + g * 4 + j;
            float vl = 0.f, vr = 0.f;
#pragma unroll
            for (int ct = 0; ct < 4; ++ct) {
                float v = acc[ct][j];
                featb[(long)row * HD + w * 64 + ct * 16 + fr] = f2b(v);
                vl = fmaf(v, aLr[ct], vl);
                vr = fmaf(v, aRr[ct], vr);
            }
            vl += __shfl_xor(vl, 1); vl += __shfl_xor(vl, 2);
            vl += __shfl_xor(vl, 4); vl += __shfl_xor(vl, 8);
            vr += __shfl_xor(vr, 1); vr += __shfl_xor(vr, 2);
            vr += __shfl_xor(vr, 4); vr += __shfl_xor(vr, 8);
            if (fr == 0) {
                el[(long)row * H + w] = vl;
                er[(long)row * H + w] = vr;
            }
        }
    } else if (bid < GEMB + PB) {
        int n = (bid - GEMB) * 256 + t;
        if (n < NN) {
            const float* row = logits + (long)n * C;
            float best = row[0]; int bi = 0;
#pragma unroll
            for (int c = 1; c < C; ++c) { float v = row[c]; if (v > best) { best = v; bi = c; } }
            pred[n] = bi;
        }
    } else {
        int e = (bid - GEMB - PB) * 256 + t;
        if (e < EE) rank[e] = atomicAdd(&deg_i[dst[e]], 1);
    }
}

// 1024-thread single-block exclusive scan -> rowptr. Shfl wave scans,
// only 2 barriers.
__global__ __launch_bounds__(1024) void k_scan(const int* __restrict__ deg_i,
                                               int* __restrict__ rowptr) {
    __shared__ int wsum[16];
    constexpr int CH = (NN + 1023) / 1024; // 10
    int t = threadIdx.x;
    int lane = t & 63, wid = t >> 6;
    int base = t * CH;
    int d[CH];
    int s = 0;
#pragma unroll
    for (int i = 0; i < CH; ++i) {
        int idx = base + i;
        d[i] = (idx < NN) ? deg_i[idx] : 0;
        s += d[i];
    }
    int incl = s;
    for (int off = 1; off < 64; off <<= 1) {
        int v = __shfl_up(incl, off);
        if (lane >= off) incl += v;
    }
    if (lane == 63) wsum[wid] = incl;
    __syncthreads();
    if (t < 16) {
        int v = wsum[t];
        int inc2 = v;
        for (int off = 1; off < 16; off <<= 1) {
            int u = __shfl_up(inc2, off);
            if (t >= off) inc2 += u;
        }
        wsum[t] = inc2 - v;
    }
    __syncthreads();
    int run = wsum[wid] + incl - s;
#pragma unroll
    for (int i = 0; i < CH; ++i) {
        int idx = base + i;
        if (idx < NN) { rowptr[idx] = run; run += d[i]; }
    }
    if (t == 1023) rowptr[NN] = run; // == EE
}

// atomic-free scatter: slot = rowptr[dst] + rank (unique by construction)
__global__ __launch_bounds__(256) void k_scatter(const int* __restrict__ src,
                                                 const int* __restrict__ dst,
                                                 const int* __restrict__ rank,
                                                 const int* __restrict__ rowptr,
                                                 int* __restrict__ ssrc) {
    int e = blockIdx.x * 256 + threadIdx.x;
    if (e >= EE) return;
    ssrc[rowptr[dst[e]] + rank[e]] = src[e];
}

// one wave per dst node. 16-edge strips; per-edge (src,pred) broadcast via
// readlane (scalar-uniform gather address) + 1 shfl for the weight.
#define EDGE(kk) { \
    int spk = __builtin_amdgcn_readlane(sp, (kk)); \
    int s_  = spk & 0xFFFF; \
    int ps_ = spk >> 16; \
    float wa = __shfl(w, (hidx << 4) | (kk)); \
    const ushort4 f = *(const ushort4*)(featb + (long)s_ * HD + (lane << 2)); \
    acc.x = fmaf(wa, b2f(f.x), acc.x); \
    acc.y = fmaf(wa, b2f(f.y), acc.y); \
    acc.z = fmaf(wa, b2f(f.z), acc.z); \
    acc.w = fmaf(wa, b2f(f.w), acc.w); \
    f1a += (ps_ == pd)   ? wa : 0.f; \
    ca  += (ps_ == cidx) ? wa : 0.f; \
}

__global__ __launch_bounds__(256) void k_agg(const int* __restrict__ rowptr,
                                             const int* __restrict__ ssrc,
                                             const float* __restrict__ el,
                                             const float* __restrict__ er,
                                             const unsigned short* __restrict__ featb,
                                             const int* __restrict__ pred,
                                             float* __restrict__ agg,
                                             float* __restrict__ f1,
                                             float* __restrict__ f2) {
    int lane = threadIdx.x & 63;
    int n = blockIdx.x * 4 + (threadIdx.x >> 6); // grid = NN/4 exactly
    int beg = rowptr[n], end = rowptr[n + 1];
    int deg = end - beg;
    int hidx = lane >> 4, cidx = lane & 15;
    float Rh = er[(long)n * H + hidx];
    int pd = pred[n];

    float4 acc = {0.f, 0.f, 0.f, 0.f};
    float dsum = 0.f, f1a = 0.f, ca = 0.f;

    for (int base = beg; base < end; base += 16) {
        int nk = end - base; if (nk > 16) nk = 16;
        float w = 0.f; int sp = 0;
        if (cidx < nk) {
            int s = ssrc[base + cidx];
            float x = el[(long)s * H + hidx] + Rh;
            x = x > 0.f ? x : 0.2f * x;
            w = __expf(x);
            if (hidx == 0) sp = s | (pred[s] << 16);
        }
        dsum += w;
        if (nk == 16) {
#pragma unroll
            for (int k = 0; k < 16; ++k) EDGE(k)
        } else {
            for (int k = 0; k < nk; ++k) EDGE(k)
        }
    }

    for (int off = 1; off < 16; off <<= 1) dsum += __shfl_xor(dsum, off);
    float invh = dsum > 0.f ? 1.f / dsum : 0.f;
    float invdeg = 1.0f / (float)(deg > 0 ? deg : 1);

    float4 o;
    o.x = acc.x * invh; o.y = acc.y * invh; o.z = acc.z * invh; o.w = acc.w * invh;
    *(float4*)(agg + (long)n * HD + (lane << 2)) = o;

    float v = fmaxf(ca * invh * invdeg, 1e-5f);
    float term = -v * logf(v);
    for (int off = 1; off < 16; off <<= 1) term += __shfl_xor(term, off);
    if (cidx == 0) {
        f1[(long)n * H + hidx] = f1a * invh * invdeg;
        f2[(long)n * H + hidx] = term;
    }
}

// single-block reduction of f1/f2 -> sums[4] (plain stores, deterministic)
__global__ __launch_bounds__(1024) void k_sum(const float* __restrict__ f1,
                                              const float* __restrict__ f2,
                                              float* __restrict__ sums) {
    __shared__ float red[16][4];
    float s1 = 0.f, q1 = 0.f, s2 = 0.f, q2 = 0.f;
    for (int i = threadIdx.x; i < NN * H; i += 1024) {
        float a = f1[i], b = f2[i];
        s1 += a; q1 = fmaf(a, a, q1);
        s2 += b; q2 = fmaf(b, b, q2);
    }
    for (int off = 32; off; off >>= 1) {
        s1 += __shfl_down(s1, off);
        q1 += __shfl_down(q1, off);
        s2 += __shfl_down(s2, off);
        q2 += __shfl_down(q2, off);
    }
    int wid = threadIdx.x >> 6;
    if ((threadIdx.x & 63) == 0) {
        red[wid][0] = s1; red[wid][1] = q1; red[wid][2] = s2; red[wid][3] = q2;
    }
    __syncthreads();
    if (threadIdx.x < 4) {
        float a = 0.f;
        for (int wv = 0; wv < 16; ++wv) a += red[wv][threadIdx.x];
        sums[threadIdx.x] = a;
    }
}

// fused: z/gate (LayerNorm'd f1,f2) + final output. 4 elems/thread,
// feat read in bf16 (f32 feat buffer eliminated).
__global__ __launch_bounds__(256) void k_out(const unsigned short* __restrict__ featb,
                                             const float* __restrict__ agg,
                                             const float* __restrict__ f1,
                                             const float* __restrict__ f2,
                                             const float* __restrict__ sums,
                                             const float* __restrict__ old_z,
                                             const float* __restrict__ tau1,
                                             const float* __restrict__ tau2,
                                             const int* __restrict__ rowptr,
                                             float* __restrict__ out,
                                             float* __restrict__ zout) {
    long i4 = ((long)blockIdx.x * 256 + threadIdx.x) * 4;
    if (i4 >= (long)NN * HD) return;
    int n = (int)(i4 >> 8);
    int h = (int)((i4 >> 6) & 3);
    int t = n * H + h;
    constexpr float invNH = 1.0f / (NN * H);
    float mu1 = sums[0] * invNH, mu2 = sums[2] * invNH;
    float v1 = fmaxf(sums[1] * invNH - mu1 * mu1, 0.f);
    float v2 = fmaxf(sums[3] * invNH - mu2 * mu2, 0.f);
    float r1 = rsqrtf(v1 + 1e-5f), r2 = rsqrtf(v2 + 1e-5f);
    float nf1 = (f1[t] - mu1) * r1;
    float nf2 = (f2[t] - mu2) * r2;
    float z = (1.f / (1.f + expf(nf1 - tau1[0]))) * (1.f / (1.f + expf(nf2 - tau2[0])));
    float gate = fminf(old_z[t], z);
    if ((i4 & 63) == 0) zout[t] = z;
    int deg = rowptr[n + 1] - rowptr[n];
    float g = gate * rsqrtf((float)(deg > 0 ? deg : 1));
    const ushort4 fb = *(const ushort4*)(featb + i4);
    const float4 ag = *(const float4*)(agg + i4);
    float4 o;
    o.x = fmaf(g, ag.x, b2f(fb.x));
    o.y = fmaf(g, ag.y, b2f(fb.y));
    o.z = fmaf(g, ag.z, b2f(fb.z));
    o.w = fmaf(g, ag.w, b2f(fb.w));
    *(float4*)(out + i4) = o;
}

extern "C" void kernel_launch(void* const* d_in, const int* in_sizes, int n_in,
                              void* d_out, int out_size, void* d_ws, size_t ws_size,
                              hipStream_t stream) {
    const float* hin    = (const float*)d_in[0];
    const float* logits = (const float*)d_in[1];
    const float* old_z  = (const float*)d_in[2];
    const float* attn_l = (const float*)d_in[3];
    const float* attn_r = (const float*)d_in[4];
    const float* Wfc    = (const float*)d_in[5];
    const float* tau1   = (const float*)d_in[6];
    const float* tau2   = (const float*)d_in[7];
    const int*   src    = (const int*)d_in[8];
    const int*   dst    = (const int*)d_in[9];
    float* out = (float*)d_out;
    float* ws  = (float*)d_ws;

    unsigned short* featb = (unsigned short*)(ws + OFF_FB);
    unsigned short* wp    = (unsigned short*)(ws + OFF_WP);
    unsigned short* ha    = (unsigned short*)(ws + OFF_HA);
    int* pred   = (int*)(ws + OFF_PRED);
    int* ssrc   = (int*)(ws + OFF_SSRC);
    int* rowptr = (int*)(ws + OFF_ROWP);
    int* rank   = (int*)(ws + OFF_RANK);
    int* deg_i  = (int*)(ws + OFF_DEGI);
    float* sums = ws + OFF_SUM;

    k_pack   <<<32 + ZB + HAB, 256, 0, stream>>>(Wfc, hin, wp, ha, deg_i);
    k_main   <<<GEMB + PB + CB, 256, 0, stream>>>(ha, wp, attn_l, attn_r, logits, dst,
                                                  featb, ws + OFF_EL, ws + OFF_ER,
                                                  pred, deg_i, rank);
    k_scan   <<<1, 1024, 0, stream>>>(deg_i, rowptr);
    k_scatter<<<(EE + 255) / 256, 256, 0, stream>>>(src, dst, rank, rowptr, ssrc);
    k_agg    <<<NN / 4, 256, 0, stream>>>(rowptr, ssrc, ws + OFF_EL, ws + OFF_ER,
                                          featb, pred,
                                          ws + OFF_AGG, ws + OFF_F1, ws + OFF_F2);
    k_sum    <<<1, 1024, 0, stream>>>(ws + OFF_F1, ws + OFF_F2, sums);
    k_out    <<<(NN * HD / 4 + 255) / 256, 256, 0, stream>>>(featb, ws + OFF_AGG,
                                                             ws + OFF_F1, ws + OFF_F2, sums,
                                                             old_z, tau1, tau2, rowptr,
                                                             out, out + (long)NN * HD);
}